// Round 5
// baseline (1406.793 us; speedup 1.0000x reference)
//
#include <hip/hip_runtime.h>
#include <math.h>

#define BB   32
#define HH   56
#define WWI  56
#define CC   96
#define NHD  3
#define WSZ  7
#define SHF  3
#define NTK  49
#define NWIN 64
#define HDM  32
#define TOT  (BB*HH*WWI)               // 100352
#define QKSCALE 0.17677669529663687f
#define LEPS 1e-3f
#define RSQ2 0.7071067811865476f

typedef __attribute__((ext_vector_type(8))) short s8v;   // 8 bf16 (4 VGPRs)
typedef __attribute__((ext_vector_type(4))) float fx4;   // 4 fp32
typedef unsigned long long ull_t;

#define MFMA16(a,b,c) __builtin_amdgcn_mfma_f32_16x16x32_bf16((a),(b),(c),0,0,0)

__device__ __forceinline__ unsigned short f2bf(float f) {
    union { float f; unsigned u; } v; v.f = f;
    unsigned r = v.u + 0x7FFFu + ((v.u >> 16) & 1u);
    return (unsigned short)(r >> 16);
}
__device__ __forceinline__ float bfl(unsigned u) { return __uint_as_float(u << 16); }
__device__ __forceinline__ float bfh(unsigned u) { return __uint_as_float(u & 0xFFFF0000u); }

// windowed token id -> original flat token id (roll(-3,-3) + window partition)
__device__ __forceinline__ int wtok_to_orig(int wt) {
    int win = wt / NTK;
    int p   = wt - win * NTK;
    int b   = win >> 6;
    int w   = win & 63;
    int wi = w >> 3, wj = w & 7;
    int pi = p / WSZ, pj = p - pi * WSZ;
    int r = wi * WSZ + pi + SHF; if (r >= HH) r -= HH;
    int c = wj * WSZ + pj + SHF; if (c >= WWI) c -= WWI;
    return b * (HH * WWI) + r * WWI + c;
}

// ---------- P0: weight transpose + bf16 convert ----------
extern "C" __global__ void p0_prep(const float* __restrict__ qw, const float* __restrict__ pw,
                                   const float* __restrict__ w1, const float* __restrict__ w2,
                                   unsigned short* __restrict__ wsw)
{
    int i = blockIdx.x * 256 + threadIdx.x;
    if (i < 27648) {                       // qwt[288][96]
        int n = i / 96, k = i - n * 96;
        wsw[i] = f2bf(qw[k * 288 + n]);
    } else if (i < 36864) {                // pwt[96][96]
        int j = i - 27648; int n = j / 96, k = j - n * 96;
        wsw[i] = f2bf(pw[k * 96 + n]);
    } else if (i < 73728) {                // w1t[384][96]
        int j = i - 36864; int n = j / 96, k = j - n * 96;
        wsw[i] = f2bf(w1[k * 384 + n]);
    } else if (i < 110592) {               // w2t[96][384]
        int j = i - 73728; int n = j / 384, k = j - n * 384;
        wsw[i] = f2bf(w2[k * 96 + n]);
    }
}

// ---------- K1: gather + LN1 + QKV MFMA GEMM -> qkv[TOT][288] fp32 ----------
#define LDH 104
extern "C" __global__ void __launch_bounds__(256, 4) k1_qkv(
    const float* __restrict__ x, const float* __restrict__ g1, const float* __restrict__ b1,
    const unsigned short* __restrict__ qwt, const float* __restrict__ qb,
    float* __restrict__ qkv)
{
    __shared__ unsigned short Hn[64 * LDH];
    __shared__ unsigned short Wc[96 * LDH];
    const int tid = threadIdx.x, wave = tid >> 6, lane = tid & 63;
    const int blk = blockIdx.x;

    { // LN1: 4 lanes per token
        const int tl = tid >> 2, q4 = tid & 3;
        const int orig = wtok_to_orig(blk * 64 + tl);
        const float* row = x + (size_t)orig * CC + q4 * 24;
        float h[24];
        #pragma unroll
        for (int j = 0; j < 6; ++j) {
            fx4 v = *reinterpret_cast<const fx4*>(row + 4 * j);
            h[4*j]=v.x; h[4*j+1]=v.y; h[4*j+2]=v.z; h[4*j+3]=v.w;
        }
        float s = 0.f, s2 = 0.f;
        #pragma unroll
        for (int j = 0; j < 24; ++j) { s += h[j]; s2 = fmaf(h[j], h[j], s2); }
        s  += __shfl_xor(s, 1);  s  += __shfl_xor(s, 2);
        s2 += __shfl_xor(s2, 1); s2 += __shfl_xor(s2, 2);
        const float mu = s * (1.f/CC);
        const float rs = rsqrtf(s2 * (1.f/CC) - mu * mu + LEPS);
        unsigned short t[24];
        #pragma unroll
        for (int j = 0; j < 24; ++j) {
            int c = q4 * 24 + j;
            t[j] = f2bf((h[j] - mu) * rs * g1[c] + b1[c]);
        }
        #pragma unroll
        for (int j = 0; j < 6; ++j) {
            ull_t pk = (ull_t)t[4*j] | ((ull_t)t[4*j+1] << 16) |
                       ((ull_t)t[4*j+2] << 32) | ((ull_t)t[4*j+3] << 48);
            *reinterpret_cast<ull_t*>(&Hn[tl * LDH + q4 * 24 + 4*j]) = pk;
        }
    }

    for (int ck = 0; ck < 3; ++ck) {
        for (int i = tid; i < 96 * 12; i += 256) {
            int r = i / 12, k0 = (i - r * 12) * 8;
            *reinterpret_cast<s8v*>(&Wc[r * LDH + k0]) =
                *reinterpret_cast<const s8v*>(&qwt[(ck * 96 + r) * 96 + k0]);
        }
        __syncthreads();
        fx4 acc[6];
        #pragma unroll
        for (int nt = 0; nt < 6; ++nt) acc[nt] = (fx4){0.f,0.f,0.f,0.f};
        #pragma unroll
        for (int ks = 0; ks < 3; ++ks) {
            s8v a = *reinterpret_cast<const s8v*>(&Hn[(wave*16 + (lane&15))*LDH + ks*32 + (lane>>4)*8]);
            #pragma unroll
            for (int nt = 0; nt < 6; ++nt) {
                s8v b = *reinterpret_cast<const s8v*>(&Wc[(nt*16 + (lane&15))*LDH + ks*32 + (lane>>4)*8]);
                acc[nt] = MFMA16(a, b, acc[nt]);
            }
        }
        const int rowb = blk * 64 + wave * 16 + (lane >> 4) * 4;
        #pragma unroll
        for (int nt = 0; nt < 6; ++nt) {
            const int col = ck * 96 + nt * 16 + (lane & 15);
            const float qbc = qb[col];
            #pragma unroll
            for (int r = 0; r < 4; ++r)
                qkv[(size_t)(rowb + r) * 288 + col] = acc[nt][r] + qbc;
        }
        __syncthreads();
    }
}

// ---------- K2: attention, one wave per (window, head), K/V in LDS as bf16 ----------
// LDS-return-BW was the binding pipe (784 b128 broadcasts/wave, rounds 2&4
// both 129us at 2 blocks/CU). bf16 K/V halves LDS reads AND footprint
// (27KB -> VGPR-capped 4 blocks/CU). Keep (256,2): (256,3) spilled s[49].
extern "C" __global__ void __launch_bounds__(256, 2) k2_attn(
    float* __restrict__ qkv, const float* __restrict__ btab)
{
    __shared__ unsigned short KV[4][2][NTK][HDM];   // bf16, 25088 B
    __shared__ float BT[169 * NHD];                 // 2028 B
    const int tid = threadIdx.x, wave = tid >> 6, lane = tid & 63;
    const int task = blockIdx.x * 4 + wave;
    const int win = task / 3, h = task - win * 3;
    const int g0  = win * NTK;
    const int tc  = lane < NTK ? lane : NTK - 1;
    const int w   = win & 63;
    const int wi = w >> 3, wj = w & 7;
    const int it = tc / WSZ, jt = tc - it * WSZ;
    const int gi = wi * WSZ + it, gj = wj * WSZ + jt;
    const int labt = (gi < 49 ? 0 : (gi < 53 ? 1 : 2)) * 3 + (gj < 49 ? 0 : (gj < 53 ? 1 : 2));

    for (int i = tid; i < 169 * NHD; i += 256) BT[i] = btab[i];
    // stage this wave's K,V as bf16
    for (int i = lane; i < NTK * 8; i += 64) {
        int u = i >> 3, c = (i & 7) * 4;
        fx4 kv = *reinterpret_cast<const fx4*>(&qkv[(size_t)(g0 + u) * 288 +  96 + h * HDM + c]);
        fx4 vv = *reinterpret_cast<const fx4*>(&qkv[(size_t)(g0 + u) * 288 + 192 + h * HDM + c]);
        ull_t pk = (ull_t)f2bf(kv.x) | ((ull_t)f2bf(kv.y) << 16) |
                   ((ull_t)f2bf(kv.z) << 32) | ((ull_t)f2bf(kv.w) << 48);
        ull_t pv = (ull_t)f2bf(vv.x) | ((ull_t)f2bf(vv.y) << 16) |
                   ((ull_t)f2bf(vv.z) << 32) | ((ull_t)f2bf(vv.w) << 48);
        *reinterpret_cast<ull_t*>(&KV[wave][0][u][c]) = pk;
        *reinterpret_cast<ull_t*>(&KV[wave][1][u][c]) = pv;
    }
    __syncthreads();

    float q[HDM];
    #pragma unroll
    for (int j = 0; j < 8; ++j) {
        fx4 v = *reinterpret_cast<const fx4*>(&qkv[(size_t)(g0 + tc) * 288 + h * HDM + 4 * j]);
        q[4*j]   = v.x * QKSCALE; q[4*j+1] = v.y * QKSCALE;
        q[4*j+2] = v.z * QKSCALE; q[4*j+3] = v.w * QKSCALE;
    }

    float s[NTK];
    #pragma unroll
    for (int u = 0; u < NTK; ++u) {
        const uint4* kr = reinterpret_cast<const uint4*>(&KV[wave][0][u][0]);
        float a0 = 0.f, a1 = 0.f;
        #pragma unroll
        for (int c = 0; c < 4; ++c) {
            uint4 kw = kr[c];
            a0 = fmaf(bfl(kw.x), q[8*c+0], a0); a1 = fmaf(bfh(kw.x), q[8*c+1], a1);
            a0 = fmaf(bfl(kw.y), q[8*c+2], a0); a1 = fmaf(bfh(kw.y), q[8*c+3], a1);
            a0 = fmaf(bfl(kw.z), q[8*c+4], a0); a1 = fmaf(bfh(kw.z), q[8*c+5], a1);
            a0 = fmaf(bfl(kw.w), q[8*c+6], a0); a1 = fmaf(bfh(kw.w), q[8*c+7], a1);
        }
        const int iu = u / WSZ, ju = u - iu * WSZ;
        const int bidx = (jt - ju + (WSZ-1)) * (2*WSZ-1) + (it - iu + (WSZ-1));
        const int gui = wi * WSZ + iu, guj = wj * WSZ + ju;
        const int labu = (gui < 49 ? 0 : (gui < 53 ? 1 : 2)) * 3 + (guj < 49 ? 0 : (guj < 53 ? 1 : 2));
        s[u] = a0 + a1 + BT[bidx * NHD + h] + (labu == labt ? 0.f : -100.f);
    }

    #pragma unroll 1
    for (int pass = 0; pass < 2; ++pass) {
        float mx = s[0];
        #pragma unroll
        for (int u = 1; u < NTK; ++u) mx = fmaxf(mx, s[u]);
        float sum = 0.f;
        #pragma unroll
        for (int u = 0; u < NTK; ++u) { s[u] = __expf(s[u] - mx); sum += s[u]; }
        const float inv = 1.f / sum;
        #pragma unroll
        for (int u = 0; u < NTK; ++u) s[u] *= inv;
    }

    float ov[HDM];
    #pragma unroll
    for (int j = 0; j < HDM; ++j) ov[j] = 0.f;
    #pragma unroll
    for (int u = 0; u < NTK; ++u) {
        const float sv = s[u];
        const uint4* vr = reinterpret_cast<const uint4*>(&KV[wave][1][u][0]);
        #pragma unroll
        for (int c = 0; c < 4; ++c) {
            uint4 vw = vr[c];
            ov[8*c+0] = fmaf(bfl(vw.x), sv, ov[8*c+0]); ov[8*c+1] = fmaf(bfh(vw.x), sv, ov[8*c+1]);
            ov[8*c+2] = fmaf(bfl(vw.y), sv, ov[8*c+2]); ov[8*c+3] = fmaf(bfh(vw.y), sv, ov[8*c+3]);
            ov[8*c+4] = fmaf(bfl(vw.z), sv, ov[8*c+4]); ov[8*c+5] = fmaf(bfh(vw.z), sv, ov[8*c+5]);
            ov[8*c+6] = fmaf(bfl(vw.w), sv, ov[8*c+6]); ov[8*c+7] = fmaf(bfh(vw.w), sv, ov[8*c+7]);
        }
    }
    if (lane < NTK) {
        #pragma unroll
        for (int j = 0; j < 8; ++j) {
            fx4 o4 = (fx4){ov[4*j], ov[4*j+1], ov[4*j+2], ov[4*j+3]};
            *reinterpret_cast<fx4*>(&qkv[(size_t)(g0 + lane) * 288 + h * HDM + 4 * j]) = o4;
        }
    }
}

// ---------- K2b: proj MFMA GEMM + residual + un-shift scatter -> d_out ----------
extern "C" __global__ void __launch_bounds__(256, 4) k2b_proj(
    const float* __restrict__ qkv, const unsigned short* __restrict__ pwt,
    const float* __restrict__ pb, const float* __restrict__ x, float* __restrict__ out)
{
    __shared__ unsigned short Ao[64 * LDH];
    __shared__ unsigned short Wc[96 * LDH];
    const int tid = threadIdx.x, wave = tid >> 6, lane = tid & 63;
    const int blk = blockIdx.x;

    {
        const int tl = tid >> 2, q4 = tid & 3;
        const float* row = qkv + (size_t)(blk * 64 + tl) * 288 + q4 * 24;
        unsigned short t[24];
        #pragma unroll
        for (int j = 0; j < 6; ++j) {
            fx4 v = *reinterpret_cast<const fx4*>(row + 4 * j);
            t[4*j]=f2bf(v.x); t[4*j+1]=f2bf(v.y); t[4*j+2]=f2bf(v.z); t[4*j+3]=f2bf(v.w);
        }
        #pragma unroll
        for (int j = 0; j < 6; ++j) {
            ull_t pk = (ull_t)t[4*j] | ((ull_t)t[4*j+1] << 16) |
                       ((ull_t)t[4*j+2] << 32) | ((ull_t)t[4*j+3] << 48);
            *reinterpret_cast<ull_t*>(&Ao[tl * LDH + q4 * 24 + 4*j]) = pk;
        }
    }
    for (int i = tid; i < 96 * 12; i += 256) {
        int r = i / 12, k0 = (i - r * 12) * 8;
        *reinterpret_cast<s8v*>(&Wc[r * LDH + k0]) =
            *reinterpret_cast<const s8v*>(&pwt[r * 96 + k0]);
    }
    __syncthreads();

    fx4 acc[6];
    #pragma unroll
    for (int nt = 0; nt < 6; ++nt) acc[nt] = (fx4){0.f,0.f,0.f,0.f};
    #pragma unroll
    for (int ks = 0; ks < 3; ++ks) {
        s8v a = *reinterpret_cast<const s8v*>(&Ao[(wave*16 + (lane&15))*LDH + ks*32 + (lane>>4)*8]);
        #pragma unroll
        for (int nt = 0; nt < 6; ++nt) {
            s8v b = *reinterpret_cast<const s8v*>(&Wc[(nt*16 + (lane&15))*LDH + ks*32 + (lane>>4)*8]);
            acc[nt] = MFMA16(a, b, acc[nt]);
        }
    }
    int orig[4];
    #pragma unroll
    for (int r = 0; r < 4; ++r)
        orig[r] = wtok_to_orig(blk * 64 + wave * 16 + (lane >> 4) * 4 + r);
    #pragma unroll
    for (int nt = 0; nt < 6; ++nt) {
        const int col = nt * 16 + (lane & 15);
        const float pbc = pb[col];
        #pragma unroll
        for (int r = 0; r < 4; ++r) {
            const size_t idx = (size_t)orig[r] * CC + col;
            out[idx] = acc[nt][r] + pbc + x[idx];
        }
    }
}

// ---------- K3: LN2 + fc1 + gelu^2 + fc2 + residual (MFMA, NC=64 chunks) ----------
#define LDA 72
extern "C" __global__ void __launch_bounds__(256, 3) k3_mlp(
    float* __restrict__ xio, const float* __restrict__ g2, const float* __restrict__ b2,
    const unsigned short* __restrict__ w1t, const float* __restrict__ bf1,
    const unsigned short* __restrict__ w2t, const float* __restrict__ bf2)
{
    __shared__ unsigned short Hn[64 * LDH];
    __shared__ unsigned short W1c[64 * LDH];
    __shared__ unsigned short Ac[64 * LDA];
    __shared__ unsigned short W2c[96 * LDA];
    const int tid = threadIdx.x, wave = tid >> 6, lane = tid & 63;
    const int blk = blockIdx.x;

    {
        const int tl = tid >> 2, q4 = tid & 3;
        const float* row = xio + (size_t)(blk * 64 + tl) * CC + q4 * 24;
        float h[24];
        #pragma unroll
        for (int j = 0; j < 6; ++j) {
            fx4 v = *reinterpret_cast<const fx4*>(row + 4 * j);
            h[4*j]=v.x; h[4*j+1]=v.y; h[4*j+2]=v.z; h[4*j+3]=v.w;
        }
        float s = 0.f, s2 = 0.f;
        #pragma unroll
        for (int j = 0; j < 24; ++j) { s += h[j]; s2 = fmaf(h[j], h[j], s2); }
        s  += __shfl_xor(s, 1);  s  += __shfl_xor(s, 2);
        s2 += __shfl_xor(s2, 1); s2 += __shfl_xor(s2, 2);
        const float mu = s * (1.f/CC);
        const float rs = rsqrtf(s2 * (1.f/CC) - mu * mu + LEPS);
        unsigned short t[24];
        #pragma unroll
        for (int j = 0; j < 24; ++j) {
            int c = q4 * 24 + j;
            t[j] = f2bf((h[j] - mu) * rs * g2[c] + b2[c]);
        }
        #pragma unroll
        for (int j = 0; j < 6; ++j) {
            ull_t pk = (ull_t)t[4*j] | ((ull_t)t[4*j+1] << 16) |
                       ((ull_t)t[4*j+2] << 32) | ((ull_t)t[4*j+3] << 48);
            *reinterpret_cast<ull_t*>(&Hn[tl * LDH + q4 * 24 + 4*j]) = pk;
        }
    }

    fx4 oacc[6];
    #pragma unroll
    for (int nt = 0; nt < 6; ++nt) oacc[nt] = (fx4){0.f,0.f,0.f,0.f};

    for (int ck = 0; ck < 6; ++ck) {
        for (int i = tid; i < 64 * 12; i += 256) {
            int r = i / 12, k0 = (i - r * 12) * 8;
            *reinterpret_cast<s8v*>(&W1c[r * LDH + k0]) =
                *reinterpret_cast<const s8v*>(&w1t[(ck * 64 + r) * 96 + k0]);
        }
        for (int i = tid; i < 96 * 8; i += 256) {
            int r = i / 8, k0 = (i - r * 8) * 8;
            *reinterpret_cast<s8v*>(&W2c[r * LDA + k0]) =
                *reinterpret_cast<const s8v*>(&w2t[r * 384 + ck * 64 + k0]);
        }
        __syncthreads();

        fx4 a1[4];
        #pragma unroll
        for (int nt = 0; nt < 4; ++nt) a1[nt] = (fx4){0.f,0.f,0.f,0.f};
        #pragma unroll
        for (int ks = 0; ks < 3; ++ks) {
            s8v a = *reinterpret_cast<const s8v*>(&Hn[(wave*16 + (lane&15))*LDH + ks*32 + (lane>>4)*8]);
            #pragma unroll
            for (int nt = 0; nt < 4; ++nt) {
                s8v b = *reinterpret_cast<const s8v*>(&W1c[(nt*16 + (lane&15))*LDH + ks*32 + (lane>>4)*8]);
                a1[nt] = MFMA16(a, b, a1[nt]);
            }
        }
        #pragma unroll
        for (int nt = 0; nt < 4; ++nt) {
            const float bb = bf1[ck * 64 + nt * 16 + (lane & 15)];
            #pragma unroll
            for (int r = 0; r < 4; ++r) {
                float v0 = a1[nt][r] + bb;
                float v1 = 0.5f * v0 * (1.f + erff(v0 * RSQ2));
                float v2 = 0.5f * v1 * (1.f + erff(v1 * RSQ2));
                Ac[(wave*16 + (lane>>4)*4 + r) * LDA + nt*16 + (lane&15)] = f2bf(v2);
            }
        }
        __syncthreads();

        #pragma unroll
        for (int ks = 0; ks < 2; ++ks) {
            s8v a = *reinterpret_cast<const s8v*>(&Ac[(wave*16 + (lane&15))*LDA + ks*32 + (lane>>4)*8]);
            #pragma unroll
            for (int nt = 0; nt < 6; ++nt) {
                s8v b = *reinterpret_cast<const s8v*>(&W2c[(nt*16 + (lane&15))*LDA + ks*32 + (lane>>4)*8]);
                oacc[nt] = MFMA16(a, b, oacc[nt]);
            }
        }
        __syncthreads();
    }

    const int rowb = blk * 64 + wave * 16 + (lane >> 4) * 4;
    #pragma unroll
    for (int nt = 0; nt < 6; ++nt) {
        const int col = nt * 16 + (lane & 15);
        const float bb = bf2[col];
        #pragma unroll
        for (int r = 0; r < 4; ++r) {
            const size_t idx = (size_t)(rowb + r) * CC + col;
            xio[idx] = xio[idx] + oacc[nt][r] + bb;
        }
    }
}

extern "C" void kernel_launch(void* const* d_in, const int* in_sizes, int n_in,
                              void* d_out, int out_size, void* d_ws, size_t ws_size,
                              hipStream_t stream)
{
    const float* x    = (const float*)d_in[0];
    const float* n1g  = (const float*)d_in[1];
    const float* n1b  = (const float*)d_in[2];
    const float* qw   = (const float*)d_in[3];
    const float* qb   = (const float*)d_in[4];
    const float* btab = (const float*)d_in[5];
    const float* pw   = (const float*)d_in[6];
    const float* pb   = (const float*)d_in[7];
    const float* n2g  = (const float*)d_in[8];
    const float* n2b  = (const float*)d_in[9];
    const float* w1   = (const float*)d_in[10];
    const float* bf1  = (const float*)d_in[11];
    const float* w2   = (const float*)d_in[12];
    const float* bf2  = (const float*)d_in[13];
    float* out = (float*)d_out;

    float* qkv = (float*)d_ws;                                    // TOT*288 fp32
    unsigned short* wbf = (unsigned short*)((char*)d_ws + (size_t)TOT * 288 * 4);
    unsigned short* qwt = wbf;
    unsigned short* pwt = qwt + 288 * 96;
    unsigned short* w1t = pwt + 96 * 96;
    unsigned short* w2t = w1t + 384 * 96;

    p0_prep <<<432, 256, 0, stream>>>(qw, pw, w1, w2, wbf);
    k1_qkv  <<<TOT/64, 256, 0, stream>>>(x, n1g, n1b, qwt, qb, qkv);
    k2_attn <<<(BB*NWIN*NHD)/4, 256, 0, stream>>>(qkv, btab);
    k2b_proj<<<TOT/64, 256, 0, stream>>>(qkv, pwt, pb, x, out);
    k3_mlp  <<<TOT/64, 256, 0, stream>>>(out, n2g, n2b, w1t, bf1, w2t, bf2);
}

// Round 6
// 189.906 us; speedup vs baseline: 7.4078x; 7.4078x over previous
//
#include <hip/hip_runtime.h>
#include <math.h>

#define BB   32
#define HH   56
#define WWI  56
#define CC   96
#define NHD  3
#define WSZ  7
#define SHF  3
#define NTK  49
#define NWIN 64
#define HDM  32
#define TOT  (BB*HH*WWI)               // 100352
#define QKSCALE 0.17677669529663687f
#define LEPS 1e-3f
#define RSQ2 0.7071067811865476f

typedef __attribute__((ext_vector_type(8))) short s8v;   // 8 bf16 (4 VGPRs)
typedef __attribute__((ext_vector_type(4))) float fx4;   // 4 fp32
typedef unsigned long long ull_t;

#define MFMA16(a,b,c) __builtin_amdgcn_mfma_f32_16x16x32_bf16((a),(b),(c),0,0,0)

__device__ __forceinline__ unsigned short f2bf(float f) {
    union { float f; unsigned u; } v; v.f = f;
    unsigned r = v.u + 0x7FFFu + ((v.u >> 16) & 1u);
    return (unsigned short)(r >> 16);
}

// windowed token id -> original flat token id (roll(-3,-3) + window partition)
__device__ __forceinline__ int wtok_to_orig(int wt) {
    int win = wt / NTK;
    int p   = wt - win * NTK;
    int b   = win >> 6;
    int w   = win & 63;
    int wi = w >> 3, wj = w & 7;
    int pi = p / WSZ, pj = p - pi * WSZ;
    int r = wi * WSZ + pi + SHF; if (r >= HH) r -= HH;
    int c = wj * WSZ + pj + SHF; if (c >= WWI) c -= WWI;
    return b * (HH * WWI) + r * WWI + c;
}

// ---------- P0: weight transpose/bf16 + combined bias+mask table ----------
// wsw layout: qwt[288][96] | pwt[96][96] | w1t[384][96] | w2t[96][384] |
//             (as float, 4B-aligned) BM[4 cls][3 h][49 m][64 n]
extern "C" __global__ void p0_prep(const float* __restrict__ qw, const float* __restrict__ pw,
                                   const float* __restrict__ w1, const float* __restrict__ w2,
                                   const float* __restrict__ btab,
                                   unsigned short* __restrict__ wsw)
{
    int i = blockIdx.x * 256 + threadIdx.x;
    if (i < 27648) {                       // qwt[288][96]
        int n = i / 96, k = i - n * 96;
        wsw[i] = f2bf(qw[k * 288 + n]);
    } else if (i < 36864) {                // pwt[96][96]
        int j = i - 27648; int n = j / 96, k = j - n * 96;
        wsw[i] = f2bf(pw[k * 96 + n]);
    } else if (i < 73728) {                // w1t[384][96]
        int j = i - 36864; int n = j / 96, k = j - n * 96;
        wsw[i] = f2bf(w1[k * 384 + n]);
    } else if (i < 110592) {               // w2t[96][384]
        int j = i - 73728; int n = j / 384, k = j - n * 384;
        wsw[i] = f2bf(w2[k * 96 + n]);
    } else if (i < 148224) {               // BM table (fp32)
        float* bm = (float*)(wsw + 110592);
        int j = i - 110592;
        int n = j & 63, mh = j >> 6;
        int m = mh % 49, t = mh / 49;
        int hd = t % 3, cls = t / 3;       // cls = (wi==7)*2 + (wj==7)
        float val = 0.f;
        if (n < 49) {
            int it = m / 7, jt = m - it * 7;
            int iu = n / 7, ju = n - iu * 7;
            int li  = (cls & 2) ? (it < 4 ? 1 : 2) : 0;
            int lj  = (cls & 1) ? (jt < 4 ? 1 : 2) : 0;
            int lui = (cls & 2) ? (iu < 4 ? 1 : 2) : 0;
            int luj = (cls & 1) ? (ju < 4 ? 1 : 2) : 0;
            int bidx = (jt - ju + 6) * 13 + (it - iu + 6);
            val = btab[bidx * 3 + hd] + ((li*3+lj) == (lui*3+luj) ? 0.f : -100.f);
        }
        bm[j] = val;
    }
}

// ---------- K1: gather + LN1 + QKV MFMA GEMM -> qkv[TOT][288] fp32 ----------
#define LDH 104
extern "C" __global__ void __launch_bounds__(256, 4) k1_qkv(
    const float* __restrict__ x, const float* __restrict__ g1, const float* __restrict__ b1,
    const unsigned short* __restrict__ qwt, const float* __restrict__ qb,
    float* __restrict__ qkv)
{
    __shared__ unsigned short Hn[64 * LDH];
    __shared__ unsigned short Wc[96 * LDH];
    const int tid = threadIdx.x, wave = tid >> 6, lane = tid & 63;
    const int blk = blockIdx.x;

    { // LN1: 4 lanes per token
        const int tl = tid >> 2, q4 = tid & 3;
        const int orig = wtok_to_orig(blk * 64 + tl);
        const float* row = x + (size_t)orig * CC + q4 * 24;
        float h[24];
        #pragma unroll
        for (int j = 0; j < 6; ++j) {
            fx4 v = *reinterpret_cast<const fx4*>(row + 4 * j);
            h[4*j]=v.x; h[4*j+1]=v.y; h[4*j+2]=v.z; h[4*j+3]=v.w;
        }
        float s = 0.f, s2 = 0.f;
        #pragma unroll
        for (int j = 0; j < 24; ++j) { s += h[j]; s2 = fmaf(h[j], h[j], s2); }
        s  += __shfl_xor(s, 1);  s  += __shfl_xor(s, 2);
        s2 += __shfl_xor(s2, 1); s2 += __shfl_xor(s2, 2);
        const float mu = s * (1.f/CC);
        const float rs = rsqrtf(s2 * (1.f/CC) - mu * mu + LEPS);
        unsigned short t[24];
        #pragma unroll
        for (int j = 0; j < 24; ++j) {
            int c = q4 * 24 + j;
            t[j] = f2bf((h[j] - mu) * rs * g1[c] + b1[c]);
        }
        #pragma unroll
        for (int j = 0; j < 6; ++j) {
            ull_t pk = (ull_t)t[4*j] | ((ull_t)t[4*j+1] << 16) |
                       ((ull_t)t[4*j+2] << 32) | ((ull_t)t[4*j+3] << 48);
            *reinterpret_cast<ull_t*>(&Hn[tl * LDH + q4 * 24 + 4*j]) = pk;
        }
    }

    for (int ck = 0; ck < 3; ++ck) {
        for (int i = tid; i < 96 * 12; i += 256) {
            int r = i / 12, k0 = (i - r * 12) * 8;
            *reinterpret_cast<s8v*>(&Wc[r * LDH + k0]) =
                *reinterpret_cast<const s8v*>(&qwt[(ck * 96 + r) * 96 + k0]);
        }
        __syncthreads();
        fx4 acc[6];
        #pragma unroll
        for (int nt = 0; nt < 6; ++nt) acc[nt] = (fx4){0.f,0.f,0.f,0.f};
        #pragma unroll
        for (int ks = 0; ks < 3; ++ks) {
            s8v a = *reinterpret_cast<const s8v*>(&Hn[(wave*16 + (lane&15))*LDH + ks*32 + (lane>>4)*8]);
            #pragma unroll
            for (int nt = 0; nt < 6; ++nt) {
                s8v b = *reinterpret_cast<const s8v*>(&Wc[(nt*16 + (lane&15))*LDH + ks*32 + (lane>>4)*8]);
                acc[nt] = MFMA16(a, b, acc[nt]);
            }
        }
        const int rowb = blk * 64 + wave * 16 + (lane >> 4) * 4;
        #pragma unroll
        for (int nt = 0; nt < 6; ++nt) {
            const int col = ck * 96 + nt * 16 + (lane & 15);
            const float qbc = qb[col];
            #pragma unroll
            for (int r = 0; r < 4; ++r)
                qkv[(size_t)(rowb + r) * 288 + col] = acc[nt][r] + qbc;
        }
        __syncthreads();
    }
}

// ---------- K2: MFMA attention, 1 wave = 1 (window, head) ----------
// Per-lane scalar attention (rounds 2-5) was LDS-BW bound or spilled; MFMA
// frags spread state across lanes: only 64 acc regs live. No max-sub in
// softmax (scores bounded <<88; shift-invariant). Pad cols forced to e=0.
extern "C" __global__ void __launch_bounds__(64, 2) k2_attn(
    float* __restrict__ qkv, const float* __restrict__ bm)
{
    __shared__ unsigned short P[64][72];   // 9216 B, pad 72 -> <=2-way conflicts
    const int lane = threadIdx.x;
    const int l15 = lane & 15, g4 = lane >> 4;
    const int task = blockIdx.x;
    const int win = task / 3, h = task - win * 3;
    const int g0  = win * NTK;
    const int w   = win & 63;
    const int cls = (((w >> 3) == 7) ? 2 : 0) + (((w & 7) == 7) ? 1 : 0);
    const float* BMh = bm + ((size_t)(cls * 3 + h)) * 49 * 64;

    // --- Q (scaled) and K fragments, fp32 -> bf16 ---
    s8v aq[4], bk[4];
    #pragma unroll
    for (int mt = 0; mt < 4; ++mt) {
        int tok = mt * 16 + l15; if (tok > 48) tok = 48;
        const float* qp = &qkv[(size_t)(g0 + tok) * 288 + h * HDM + g4 * 8];
        fx4 v0 = *reinterpret_cast<const fx4*>(qp);
        fx4 v1 = *reinterpret_cast<const fx4*>(qp + 4);
        union { s8v v; unsigned short u[8]; } pa;
        pa.u[0]=f2bf(v0.x*QKSCALE); pa.u[1]=f2bf(v0.y*QKSCALE);
        pa.u[2]=f2bf(v0.z*QKSCALE); pa.u[3]=f2bf(v0.w*QKSCALE);
        pa.u[4]=f2bf(v1.x*QKSCALE); pa.u[5]=f2bf(v1.y*QKSCALE);
        pa.u[6]=f2bf(v1.z*QKSCALE); pa.u[7]=f2bf(v1.w*QKSCALE);
        aq[mt] = pa.v;
        const float* kp = &qkv[(size_t)(g0 + tok) * 288 + 96 + h * HDM + g4 * 8];
        fx4 k0 = *reinterpret_cast<const fx4*>(kp);
        fx4 k1 = *reinterpret_cast<const fx4*>(kp + 4);
        union { s8v v; unsigned short u[8]; } pb;
        pb.u[0]=f2bf(k0.x); pb.u[1]=f2bf(k0.y); pb.u[2]=f2bf(k0.z); pb.u[3]=f2bf(k0.w);
        pb.u[4]=f2bf(k1.x); pb.u[5]=f2bf(k1.y); pb.u[6]=f2bf(k1.z); pb.u[7]=f2bf(k1.w);
        bk[mt] = pb.v;
    }

    // --- scores: 16 MFMAs (64x64, K=32) ---
    fx4 sc[4][4];
    #pragma unroll
    for (int mt = 0; mt < 4; ++mt)
        #pragma unroll
        for (int nt = 0; nt < 4; ++nt)
            sc[mt][nt] = MFMA16(aq[mt], bk[nt], ((fx4){0.f,0.f,0.f,0.f}));

    // --- +bias+mask, double softmax (no max-sub), P -> LDS bf16 ---
    #pragma unroll
    for (int mt = 0; mt < 4; ++mt) {
        #pragma unroll
        for (int r = 0; r < 4; ++r) {
            const int m = mt * 16 + g4 * 4 + r;
            const int mc = m > 48 ? 48 : m;
            float rs1 = 0.f;
            #pragma unroll
            for (int nt = 0; nt < 4; ++nt) {
                const int n = nt * 16 + l15;
                float s = sc[mt][nt][r] + BMh[mc * 64 + n];
                float e = (n < NTK) ? __expf(s) : 0.f;
                sc[mt][nt][r] = e;
                rs1 += e;
            }
            rs1 += __shfl_xor(rs1, 1); rs1 += __shfl_xor(rs1, 2);
            rs1 += __shfl_xor(rs1, 4); rs1 += __shfl_xor(rs1, 8);
            const float iv1 = 1.f / rs1;
            float rs2 = 0.f;
            #pragma unroll
            for (int nt = 0; nt < 4; ++nt) {
                const int n = nt * 16 + l15;
                float e2 = (n < NTK) ? __expf(sc[mt][nt][r] * iv1) : 0.f;
                sc[mt][nt][r] = e2;
                rs2 += e2;
            }
            rs2 += __shfl_xor(rs2, 1); rs2 += __shfl_xor(rs2, 2);
            rs2 += __shfl_xor(rs2, 4); rs2 += __shfl_xor(rs2, 8);
            const float iv2 = 1.f / rs2;
            #pragma unroll
            for (int nt = 0; nt < 4; ++nt)
                P[m][nt * 16 + l15] = f2bf(sc[mt][nt][r] * iv2);
        }
    }
    __syncthreads();

    // --- O = P @ V : 2 K-steps x (4 M x 2 N) MFMAs ---
    fx4 oc[4][2];
    #pragma unroll
    for (int mt = 0; mt < 4; ++mt) { oc[mt][0] = (fx4){0.f,0.f,0.f,0.f}; oc[mt][1] = (fx4){0.f,0.f,0.f,0.f}; }
    #pragma unroll
    for (int ks = 0; ks < 2; ++ks) {
        s8v vb[2];
        #pragma unroll
        for (int nt = 0; nt < 2; ++nt) {
            union { s8v v; unsigned short u[8]; } pv;
            #pragma unroll
            for (int j = 0; j < 8; ++j) {
                int tok = ks * 32 + g4 * 8 + j; if (tok > 48) tok = 48;
                pv.u[j] = f2bf(qkv[(size_t)(g0 + tok) * 288 + 192 + h * HDM + nt * 16 + l15]);
            }
            vb[nt] = pv.v;
        }
        #pragma unroll
        for (int mt = 0; mt < 4; ++mt) {
            s8v pa = *reinterpret_cast<const s8v*>(&P[mt * 16 + l15][ks * 32 + g4 * 8]);
            oc[mt][0] = MFMA16(pa, vb[0], oc[mt][0]);
            oc[mt][1] = MFMA16(pa, vb[1], oc[mt][1]);
        }
    }
    // store O into spent Q-slots
    #pragma unroll
    for (int mt = 0; mt < 4; ++mt) {
        #pragma unroll
        for (int r = 0; r < 4; ++r) {
            const int m = mt * 16 + g4 * 4 + r;
            if (m < NTK) {
                qkv[(size_t)(g0 + m) * 288 + h * HDM + l15]      = oc[mt][0][r];
                qkv[(size_t)(g0 + m) * 288 + h * HDM + 16 + l15] = oc[mt][1][r];
            }
        }
    }
}

// ---------- K2b: proj MFMA GEMM + residual + un-shift scatter -> d_out ----------
extern "C" __global__ void __launch_bounds__(256, 4) k2b_proj(
    const float* __restrict__ qkv, const unsigned short* __restrict__ pwt,
    const float* __restrict__ pb, const float* __restrict__ x, float* __restrict__ out)
{
    __shared__ unsigned short Ao[64 * LDH];
    __shared__ unsigned short Wc[96 * LDH];
    const int tid = threadIdx.x, wave = tid >> 6, lane = tid & 63;
    const int blk = blockIdx.x;

    {
        const int tl = tid >> 2, q4 = tid & 3;
        const float* row = qkv + (size_t)(blk * 64 + tl) * 288 + q4 * 24;
        unsigned short t[24];
        #pragma unroll
        for (int j = 0; j < 6; ++j) {
            fx4 v = *reinterpret_cast<const fx4*>(row + 4 * j);
            t[4*j]=f2bf(v.x); t[4*j+1]=f2bf(v.y); t[4*j+2]=f2bf(v.z); t[4*j+3]=f2bf(v.w);
        }
        #pragma unroll
        for (int j = 0; j < 6; ++j) {
            ull_t pk = (ull_t)t[4*j] | ((ull_t)t[4*j+1] << 16) |
                       ((ull_t)t[4*j+2] << 32) | ((ull_t)t[4*j+3] << 48);
            *reinterpret_cast<ull_t*>(&Ao[tl * LDH + q4 * 24 + 4*j]) = pk;
        }
    }
    for (int i = tid; i < 96 * 12; i += 256) {
        int r = i / 12, k0 = (i - r * 12) * 8;
        *reinterpret_cast<s8v*>(&Wc[r * LDH + k0]) =
            *reinterpret_cast<const s8v*>(&pwt[r * 96 + k0]);
    }
    __syncthreads();

    fx4 acc[6];
    #pragma unroll
    for (int nt = 0; nt < 6; ++nt) acc[nt] = (fx4){0.f,0.f,0.f,0.f};
    #pragma unroll
    for (int ks = 0; ks < 3; ++ks) {
        s8v a = *reinterpret_cast<const s8v*>(&Ao[(wave*16 + (lane&15))*LDH + ks*32 + (lane>>4)*8]);
        #pragma unroll
        for (int nt = 0; nt < 6; ++nt) {
            s8v b = *reinterpret_cast<const s8v*>(&Wc[(nt*16 + (lane&15))*LDH + ks*32 + (lane>>4)*8]);
            acc[nt] = MFMA16(a, b, acc[nt]);
        }
    }
    int orig[4];
    #pragma unroll
    for (int r = 0; r < 4; ++r)
        orig[r] = wtok_to_orig(blk * 64 + wave * 16 + (lane >> 4) * 4 + r);
    #pragma unroll
    for (int nt = 0; nt < 6; ++nt) {
        const int col = nt * 16 + (lane & 15);
        const float pbc = pb[col];
        #pragma unroll
        for (int r = 0; r < 4; ++r) {
            const size_t idx = (size_t)orig[r] * CC + col;
            out[idx] = acc[nt][r] + pbc + x[idx];
        }
    }
}

// ---------- K3: LN2 + fc1 + gelu^2 + fc2 + residual (MFMA, NC=64 chunks) ----------
#define LDA 72
extern "C" __global__ void __launch_bounds__(256, 3) k3_mlp(
    float* __restrict__ xio, const float* __restrict__ g2, const float* __restrict__ b2,
    const unsigned short* __restrict__ w1t, const float* __restrict__ bf1,
    const unsigned short* __restrict__ w2t, const float* __restrict__ bf2)
{
    __shared__ unsigned short Hn[64 * LDH];
    __shared__ unsigned short W1c[64 * LDH];
    __shared__ unsigned short Ac[64 * LDA];
    __shared__ unsigned short W2c[96 * LDA];
    const int tid = threadIdx.x, wave = tid >> 6, lane = tid & 63;
    const int blk = blockIdx.x;

    {
        const int tl = tid >> 2, q4 = tid & 3;
        const float* row = xio + (size_t)(blk * 64 + tl) * CC + q4 * 24;
        float h[24];
        #pragma unroll
        for (int j = 0; j < 6; ++j) {
            fx4 v = *reinterpret_cast<const fx4*>(row + 4 * j);
            h[4*j]=v.x; h[4*j+1]=v.y; h[4*j+2]=v.z; h[4*j+3]=v.w;
        }
        float s = 0.f, s2 = 0.f;
        #pragma unroll
        for (int j = 0; j < 24; ++j) { s += h[j]; s2 = fmaf(h[j], h[j], s2); }
        s  += __shfl_xor(s, 1);  s  += __shfl_xor(s, 2);
        s2 += __shfl_xor(s2, 1); s2 += __shfl_xor(s2, 2);
        const float mu = s * (1.f/CC);
        const float rs = rsqrtf(s2 * (1.f/CC) - mu * mu + LEPS);
        unsigned short t[24];
        #pragma unroll
        for (int j = 0; j < 24; ++j) {
            int c = q4 * 24 + j;
            t[j] = f2bf((h[j] - mu) * rs * g2[c] + b2[c]);
        }
        #pragma unroll
        for (int j = 0; j < 6; ++j) {
            ull_t pk = (ull_t)t[4*j] | ((ull_t)t[4*j+1] << 16) |
                       ((ull_t)t[4*j+2] << 32) | ((ull_t)t[4*j+3] << 48);
            *reinterpret_cast<ull_t*>(&Hn[tl * LDH + q4 * 24 + 4*j]) = pk;
        }
    }

    fx4 oacc[6];
    #pragma unroll
    for (int nt = 0; nt < 6; ++nt) oacc[nt] = (fx4){0.f,0.f,0.f,0.f};

    for (int ck = 0; ck < 6; ++ck) {
        for (int i = tid; i < 64 * 12; i += 256) {
            int r = i / 12, k0 = (i - r * 12) * 8;
            *reinterpret_cast<s8v*>(&W1c[r * LDH + k0]) =
                *reinterpret_cast<const s8v*>(&w1t[(ck * 64 + r) * 96 + k0]);
        }
        for (int i = tid; i < 96 * 8; i += 256) {
            int r = i / 8, k0 = (i - r * 8) * 8;
            *reinterpret_cast<s8v*>(&W2c[r * LDA + k0]) =
                *reinterpret_cast<const s8v*>(&w2t[r * 384 + ck * 64 + k0]);
        }
        __syncthreads();

        fx4 a1[4];
        #pragma unroll
        for (int nt = 0; nt < 4; ++nt) a1[nt] = (fx4){0.f,0.f,0.f,0.f};
        #pragma unroll
        for (int ks = 0; ks < 3; ++ks) {
            s8v a = *reinterpret_cast<const s8v*>(&Hn[(wave*16 + (lane&15))*LDH + ks*32 + (lane>>4)*8]);
            #pragma unroll
            for (int nt = 0; nt < 4; ++nt) {
                s8v b = *reinterpret_cast<const s8v*>(&W1c[(nt*16 + (lane&15))*LDH + ks*32 + (lane>>4)*8]);
                a1[nt] = MFMA16(a, b, a1[nt]);
            }
        }
        #pragma unroll
        for (int nt = 0; nt < 4; ++nt) {
            const float bb = bf1[ck * 64 + nt * 16 + (lane & 15)];
            #pragma unroll
            for (int r = 0; r < 4; ++r) {
                float v0 = a1[nt][r] + bb;
                float v1 = 0.5f * v0 * (1.f + erff(v0 * RSQ2));
                float v2 = 0.5f * v1 * (1.f + erff(v1 * RSQ2));
                Ac[(wave*16 + (lane>>4)*4 + r) * LDA + nt*16 + (lane&15)] = f2bf(v2);
            }
        }
        __syncthreads();

        #pragma unroll
        for (int ks = 0; ks < 2; ++ks) {
            s8v a = *reinterpret_cast<const s8v*>(&Ac[(wave*16 + (lane&15))*LDA + ks*32 + (lane>>4)*8]);
            #pragma unroll
            for (int nt = 0; nt < 6; ++nt) {
                s8v b = *reinterpret_cast<const s8v*>(&W2c[(nt*16 + (lane&15))*LDA + ks*32 + (lane>>4)*8]);
                oacc[nt] = MFMA16(a, b, oacc[nt]);
            }
        }
        __syncthreads();
    }

    const int rowb = blk * 64 + wave * 16 + (lane >> 4) * 4;
    #pragma unroll
    for (int nt = 0; nt < 6; ++nt) {
        const int col = nt * 16 + (lane & 15);
        const float bb = bf2[col];
        #pragma unroll
        for (int r = 0; r < 4; ++r) {
            const size_t idx = (size_t)(rowb + r) * CC + col;
            xio[idx] = xio[idx] + oacc[nt][r] + bb;
        }
    }
}

extern "C" void kernel_launch(void* const* d_in, const int* in_sizes, int n_in,
                              void* d_out, int out_size, void* d_ws, size_t ws_size,
                              hipStream_t stream)
{
    const float* x    = (const float*)d_in[0];
    const float* n1g  = (const float*)d_in[1];
    const float* n1b  = (const float*)d_in[2];
    const float* qw   = (const float*)d_in[3];
    const float* qb   = (const float*)d_in[4];
    const float* btab = (const float*)d_in[5];
    const float* pw   = (const float*)d_in[6];
    const float* pb   = (const float*)d_in[7];
    const float* n2g  = (const float*)d_in[8];
    const float* n2b  = (const float*)d_in[9];
    const float* w1   = (const float*)d_in[10];
    const float* bf1  = (const float*)d_in[11];
    const float* w2   = (const float*)d_in[12];
    const float* bf2  = (const float*)d_in[13];
    float* out = (float*)d_out;

    float* qkv = (float*)d_ws;                                    // TOT*288 fp32
    unsigned short* wbf = (unsigned short*)((char*)d_ws + (size_t)TOT * 288 * 4);
    unsigned short* qwt = wbf;
    unsigned short* pwt = qwt + 288 * 96;
    unsigned short* w1t = pwt + 96 * 96;
    unsigned short* w2t = w1t + 384 * 96;
    float* bmt = (float*)(wbf + 110592);                          // [4][3][49][64]

    p0_prep <<<579, 256, 0, stream>>>(qw, pw, w1, w2, btab, wbf);
    k1_qkv  <<<TOT/64, 256, 0, stream>>>(x, n1g, n1b, qwt, qb, qkv);
    k2_attn <<<BB*NWIN*NHD, 64, 0, stream>>>(qkv, bmt);
    k2b_proj<<<TOT/64, 256, 0, stream>>>(qkv, pwt, pb, x, out);
    k3_mlp  <<<TOT/64, 256, 0, stream>>>(out, n2g, n2b, w1t, bf1, w2t, bf2);
}